// Round 1
// baseline (682.025 us; speedup 1.0000x reference)
//
#include <hip/hip_runtime.h>

#define NREL 3

// ---------------------------------------------------------------------------
// Layer-0 factorization tables:
//   x0 = [size_emb[x_size] | code_emb[x_code]]   (4 + 32 = 36)
//   x0 @ W_r   = size_emb[s] @ W_r[0:4]  + code_emb[c] @ W_r[4:36]
//   x0 @ root0 = size_emb[s] @ root[0:4] + code_emb[c] @ root[4:36]
// Tables: tS[3][15][24], tC[3][202][24], tSroot[15][24](+b0), tCroot[202][24]
// ---------------------------------------------------------------------------
__global__ void k_tables(const float* __restrict__ size_emb,  // [ns,4]
                         const float* __restrict__ code_emb,  // [nc,32]
                         const float* __restrict__ w0,        // [3,36,24]
                         const float* __restrict__ root0,     // [36,24]
                         const float* __restrict__ b0,        // [24]
                         float* __restrict__ tS, float* __restrict__ tC,
                         float* __restrict__ tSroot, float* __restrict__ tCroot,
                         int ns, int nc)
{
    int tid = blockIdx.x * blockDim.x + threadIdx.x;
    int A = NREL * ns * 24;
    int B = NREL * nc * 24;
    int C = ns * 24;
    int D = nc * 24;
    if (tid < A) {
        int d = tid % 24; int rs = tid / 24; int s = rs % ns; int r = rs / ns;
        float acc = 0.f;
        for (int k = 0; k < 4; ++k) acc += size_emb[s*4+k] * w0[(r*36+k)*24+d];
        tS[tid] = acc;
    } else if (tid < A + B) {
        int t = tid - A;
        int d = t % 24; int rc = t / 24; int c = rc % nc; int r = rc / nc;
        float acc = 0.f;
        for (int k = 0; k < 32; ++k) acc += code_emb[c*32+k] * w0[(r*36+4+k)*24+d];
        tC[t] = acc;
    } else if (tid < A + B + C) {
        int t = tid - A - B;
        int d = t % 24; int s = t / 24;
        float acc = b0[d];
        for (int k = 0; k < 4; ++k) acc += size_emb[s*4+k] * root0[k*24+d];
        tSroot[t] = acc;
    } else if (tid < A + B + C + D) {
        int t = tid - A - B - C;
        int d = t % 24; int c = t / 24;
        float acc = 0.f;
        for (int k = 0; k < 32; ++k) acc += code_emb[c*32+k] * root0[(4+k)*24+d];
        tCroot[t] = acc;
    }
}

// ---------------------------------------------------------------------------
// CSR build: count per (dst, rel) -> exclusive scan -> fill slots
// slot = { src | (et<<30), scale = 1/cnt[dst][et] }
// ---------------------------------------------------------------------------
__global__ void k_count(const int* __restrict__ dst, const int* __restrict__ et,
                        int* __restrict__ cntR, int E)
{
    int e = blockIdx.x * blockDim.x + threadIdx.x;
    if (e < E) atomicAdd(&cntR[dst[e]*3 + et[e]], 1);
}

__global__ void kscan1(const int* __restrict__ cntR, int* __restrict__ partials, int n)
{
    __shared__ int s[256];
    int t = threadIdx.x;
    int base = blockIdx.x * 1024 + t * 4;
    int sum = 0;
    #pragma unroll
    for (int j = 0; j < 4; ++j) {
        int node = base + j;
        if (node < n) sum += cntR[node*3] + cntR[node*3+1] + cntR[node*3+2];
    }
    s[t] = sum; __syncthreads();
    for (int off = 128; off > 0; off >>= 1) {
        if (t < off) s[t] += s[t + off];
        __syncthreads();
    }
    if (t == 0) partials[blockIdx.x] = s[0];
}

__global__ void kscan2(int* partials, int np)
{
    __shared__ int s[1024];
    int t = threadIdx.x;
    int v = (t < np) ? partials[t] : 0;
    s[t] = v; __syncthreads();
    for (int off = 1; off < 1024; off <<= 1) {
        int a = (t >= off) ? s[t - off] : 0;
        __syncthreads();
        s[t] += a; __syncthreads();
    }
    if (t < np) partials[t] = s[t] - v;  // exclusive
}

__global__ void kscan3(const int* __restrict__ cntR, const int* __restrict__ partials,
                       int* __restrict__ rowptr, int* __restrict__ rowfill, int n, int E)
{
    __shared__ int s[256];
    int t = threadIdx.x;
    int base = blockIdx.x * 1024 + t * 4;
    int d0 = 0, d1 = 0, d2 = 0, d3 = 0;
    if (base + 0 < n) d0 = cntR[(base+0)*3] + cntR[(base+0)*3+1] + cntR[(base+0)*3+2];
    if (base + 1 < n) d1 = cntR[(base+1)*3] + cntR[(base+1)*3+1] + cntR[(base+1)*3+2];
    if (base + 2 < n) d2 = cntR[(base+2)*3] + cntR[(base+2)*3+1] + cntR[(base+2)*3+2];
    if (base + 3 < n) d3 = cntR[(base+3)*3] + cntR[(base+3)*3+1] + cntR[(base+3)*3+2];
    int tsum = d0 + d1 + d2 + d3;
    s[t] = tsum; __syncthreads();
    for (int off = 1; off < 256; off <<= 1) {
        int a = (t >= off) ? s[t - off] : 0;
        __syncthreads();
        s[t] += a; __syncthreads();
    }
    int excl = s[t] - tsum + partials[blockIdx.x];
    if (base + 0 < n) { rowptr[base+0] = excl;            rowfill[base+0] = excl; }
    if (base + 1 < n) { rowptr[base+1] = excl+d0;         rowfill[base+1] = excl+d0; }
    if (base + 2 < n) { rowptr[base+2] = excl+d0+d1;      rowfill[base+2] = excl+d0+d1; }
    if (base + 3 < n) { rowptr[base+3] = excl+d0+d1+d2;   rowfill[base+3] = excl+d0+d1+d2; }
    if (blockIdx.x == 0 && t == 0) rowptr[n] = E;
}

__global__ void k_fill(const int* __restrict__ src, const int* __restrict__ dst,
                       const int* __restrict__ et, const int* __restrict__ cntR,
                       int* __restrict__ rowfill, uint2* __restrict__ edges, int E)
{
    int e = blockIdx.x * blockDim.x + threadIdx.x;
    if (e >= E) return;
    int d = dst[e]; int r = et[e];
    int pos = atomicAdd(&rowfill[d], 1);
    float scale = 1.0f / (float)cntR[d*3 + r];
    edges[pos] = make_uint2((unsigned)src[e] | ((unsigned)r << 30), __float_as_uint(scale));
}

// ---------------------------------------------------------------------------
// Layer 0: pure table-lookup RGCN layer (never materializes x0)
// ---------------------------------------------------------------------------
__global__ void __launch_bounds__(256) k_layer0(
    const int* __restrict__ x_size, const int* __restrict__ x_code,
    const int* __restrict__ rowptr, const uint2* __restrict__ edges,
    const float* __restrict__ tS, const float* __restrict__ tC,
    const float* __restrict__ tSroot, const float* __restrict__ tCroot,
    float* __restrict__ xout, int n, int ns, int nc)
{
    int i = blockIdx.x * blockDim.x + threadIdx.x;
    if (i >= n) return;
    float acc[24];
    {
        const float* a = tSroot + x_size[i] * 24;
        const float* b = tCroot + x_code[i] * 24;
        #pragma unroll
        for (int d = 0; d < 24; ++d) acc[d] = a[d] + b[d];
    }
    int r0 = rowptr[i], r1 = rowptr[i+1];
    for (int e = r0; e < r1; ++e) {
        uint2 sl = edges[e];
        int s = sl.x & 0x3FFFFFFF;
        int r = sl.x >> 30;
        float w = __uint_as_float(sl.y);
        const float* a = tS + (r * ns + x_size[s]) * 24;
        const float* b = tC + (r * nc + x_code[s]) * 24;
        #pragma unroll
        for (int d = 0; d < 24; ++d) acc[d] += (a[d] + b[d]) * w;
    }
    float4* o = (float4*)(xout + (size_t)i * 24);
    #pragma unroll
    for (int q = 0; q < 6; ++q)
        o[q] = make_float4(fmaxf(acc[q*4+0], 0.f), fmaxf(acc[q*4+1], 0.f),
                           fmaxf(acc[q*4+2], 0.f), fmaxf(acc[q*4+3], 0.f));
}

// ---------------------------------------------------------------------------
// Generic RGCN layer (pull over CSR), one thread per node.
// FINAL fuses the 4->2 output linear.
// ---------------------------------------------------------------------------
template<int DIN, int DOUT, bool FINAL>
__global__ void __launch_bounds__(256) k_layer(
    const float* __restrict__ xin, float* __restrict__ xout,
    const int* __restrict__ rowptr, const uint2* __restrict__ edges,
    const float* __restrict__ W,     // [3,DIN,DOUT]
    const float* __restrict__ root,  // [DIN,DOUT]
    const float* __restrict__ bias,  // [DOUT]
    const float* __restrict__ linw,  // [4,2]
    const float* __restrict__ linb,  // [2]
    float* __restrict__ finout, int n)
{
    __shared__ float sW[NREL * DIN * DOUT];
    __shared__ float sR[DIN * DOUT];
    __shared__ float sB[DOUT];
    for (int t = threadIdx.x; t < NREL*DIN*DOUT; t += blockDim.x) sW[t] = W[t];
    for (int t = threadIdx.x; t < DIN*DOUT; t += blockDim.x) sR[t] = root[t];
    if (threadIdx.x < DOUT) sB[threadIdx.x] = bias[threadIdx.x];
    __syncthreads();

    int i = blockIdx.x * blockDim.x + threadIdx.x;
    if (i >= n) return;

    float xi[DIN];
    {
        const float4* p = (const float4*)(xin + (size_t)i * DIN);
        #pragma unroll
        for (int q = 0; q < DIN/4; ++q) {
            float4 v = p[q];
            xi[q*4+0] = v.x; xi[q*4+1] = v.y; xi[q*4+2] = v.z; xi[q*4+3] = v.w;
        }
    }
    float acc[DOUT];
    #pragma unroll
    for (int d = 0; d < DOUT; ++d) acc[d] = sB[d];
    #pragma unroll
    for (int k = 0; k < DIN; ++k) {
        float v = xi[k];
        #pragma unroll
        for (int d = 0; d < DOUT; ++d) acc[d] = fmaf(v, sR[k*DOUT+d], acc[d]);
    }

    int r0 = rowptr[i], r1 = rowptr[i+1];
    for (int e = r0; e < r1; ++e) {
        uint2 sl = edges[e];
        int s = sl.x & 0x3FFFFFFF;
        int r = sl.x >> 30;
        float w = __uint_as_float(sl.y);
        const float4* p = (const float4*)(xin + (size_t)s * DIN);
        const float* we = sW + r * DIN * DOUT;
        #pragma unroll
        for (int q = 0; q < DIN/4; ++q) {
            float4 v = p[q];
            float v0 = v.x * w, v1 = v.y * w, v2 = v.z * w, v3 = v.w * w;
            #pragma unroll
            for (int d = 0; d < DOUT; ++d) {
                acc[d] = fmaf(v0, we[(q*4+0)*DOUT+d], acc[d]);
                acc[d] = fmaf(v1, we[(q*4+1)*DOUT+d], acc[d]);
                acc[d] = fmaf(v2, we[(q*4+2)*DOUT+d], acc[d]);
                acc[d] = fmaf(v3, we[(q*4+3)*DOUT+d], acc[d]);
            }
        }
    }
    #pragma unroll
    for (int d = 0; d < DOUT; ++d) acc[d] = fmaxf(acc[d], 0.f);

    if (FINAL) {
        float o0 = linb[0], o1 = linb[1];
        #pragma unroll
        for (int k = 0; k < 4; ++k) {
            o0 = fmaf(acc[k], linw[k*2+0], o0);
            o1 = fmaf(acc[k], linw[k*2+1], o1);
        }
        float2* o = (float2*)(finout + (size_t)i * 2);
        *o = make_float2(o0, o1);
    } else {
        float4* o = (float4*)(xout + (size_t)i * DOUT);
        #pragma unroll
        for (int q = 0; q < DOUT/4; ++q)
            o[q] = make_float4(acc[q*4+0], acc[q*4+1], acc[q*4+2], acc[q*4+3]);
    }
}

// ---------------------------------------------------------------------------
extern "C" void kernel_launch(void* const* d_in, const int* in_sizes, int n_in,
                              void* d_out, int out_size, void* d_ws, size_t ws_size,
                              hipStream_t stream)
{
    const int*   x_code    = (const int*)d_in[0];
    const int*   x_size    = (const int*)d_in[1];
    const int*   edge_index= (const int*)d_in[2];
    const int*   edge_type = (const int*)d_in[3];
    const float* size_emb  = (const float*)d_in[4];
    const float* code_emb  = (const float*)d_in[5];
    const float* w0 = (const float*)d_in[6];  const float* root0 = (const float*)d_in[7];  const float* b0 = (const float*)d_in[8];
    const float* w1 = (const float*)d_in[9];  const float* root1 = (const float*)d_in[10]; const float* b1 = (const float*)d_in[11];
    const float* w2 = (const float*)d_in[12]; const float* root2 = (const float*)d_in[13]; const float* b2 = (const float*)d_in[14];
    const float* w3 = (const float*)d_in[15]; const float* root3 = (const float*)d_in[16]; const float* b3 = (const float*)d_in[17];
    const float* lin_w = (const float*)d_in[18];
    const float* lin_b = (const float*)d_in[19];

    int n  = in_sizes[0];
    int E  = in_sizes[3];
    int ns = in_sizes[4] / 4;    // 15
    int nc = in_sizes[5] / 32;   // 202
    const int* esrc = edge_index;
    const int* edst = edge_index + E;

    // workspace carve-up (all offsets 256B-aligned); total ~196 MB
    char* ws = (char*)d_ws;
    size_t off = 0;
    auto alloc = [&](size_t bytes) -> void* {
        void* p = ws + off;
        off = (off + bytes + 255) & ~(size_t)255;
        return p;
    };
    float* bufA    = (float*)alloc((size_t)n * 24 * 4);       // x1, later x3
    float* bufB    = (float*)alloc((size_t)n * 16 * 4);       // x2
    int*   rowptr  = (int*)  alloc(((size_t)n + 1) * 4);
    int*   rowfill = (int*)  alloc((size_t)n * 4);
    uint2* edges   = (uint2*)alloc((size_t)E * 8);
    int*   cntR    = (int*)  alloc((size_t)n * 3 * 4);
    int*   partials= (int*)  alloc(4096 * 4);
    float* tS      = (float*)alloc((size_t)NREL * ns * 24 * 4);
    float* tC      = (float*)alloc((size_t)NREL * nc * 24 * 4);
    float* tSroot  = (float*)alloc((size_t)ns * 24 * 4);
    float* tCroot  = (float*)alloc((size_t)nc * 24 * 4);

    hipMemsetAsync(cntR, 0, (size_t)n * 3 * 4, stream);

    const int tb = 256;
    int tableThreads = NREL*ns*24 + NREL*nc*24 + ns*24 + nc*24;
    k_tables<<<(tableThreads + tb - 1)/tb, tb, 0, stream>>>(
        size_emb, code_emb, w0, root0, b0, tS, tC, tSroot, tCroot, ns, nc);

    k_count<<<(E + tb - 1)/tb, tb, 0, stream>>>(edst, edge_type, cntR, E);

    int nblk = (n + 1023) / 1024;   // 977 for n=1e6 (must be <= 1024)
    kscan1<<<nblk, 256, 0, stream>>>(cntR, partials, n);
    kscan2<<<1, 1024, 0, stream>>>(partials, nblk);
    kscan3<<<nblk, 256, 0, stream>>>(cntR, partials, rowptr, rowfill, n, E);

    k_fill<<<(E + tb - 1)/tb, tb, 0, stream>>>(esrc, edst, edge_type, cntR, rowfill, edges, E);

    int gl = (n + tb - 1) / tb;
    k_layer0<<<gl, tb, 0, stream>>>(x_size, x_code, rowptr, edges,
                                    tS, tC, tSroot, tCroot, bufA, n, ns, nc);
    k_layer<24,16,false><<<gl, tb, 0, stream>>>(bufA, bufB, rowptr, edges,
                                                w1, root1, b1, nullptr, nullptr, nullptr, n);
    k_layer<16, 8,false><<<gl, tb, 0, stream>>>(bufB, bufA, rowptr, edges,
                                                w2, root2, b2, nullptr, nullptr, nullptr, n);
    k_layer< 8, 4,true ><<<gl, tb, 0, stream>>>(bufA, nullptr, rowptr, edges,
                                                w3, root3, b3, lin_w, lin_b, (float*)d_out, n);
}